// Round 5
// baseline (220.670 us; speedup 1.0000x reference)
//
#include <hip/hip_runtime.h>
#include <hip/hip_bf16.h>

// KAN layer as augmented GEMM:
//   Af[b, c*1024+i] = c==0 ? silu(x[b,i]) : basis_{c-1}(x[b,i])   (bf16)
//   Wf[o, c*1024+i] = c==0 ? base_w[o,i]  : spline_w[o,i,c-1]     (bf16)
//   out = Af @ Wf^T  (fp32 accum via MFMA)
//
// GEMM: 256x256 tile, BK=64, 8 waves (2Mx4N -> 128x64/wave, 42.7 FLOP per
// LDS-byte vs 32.8 at 64x64), A ring-3 (distance-2, HBM stream) + B dbuf
// (distance-1, L2-resident) = 160KiB LDS, counted vmcnt(4), 4 phases x
// 16 MFMA with B-fragments hoisted in phase 0, (row&7) 16B-slot XOR
// swizzle (0-conflict proven), T5 setprio, T1 bijective XCD swizzle,
// split-K=2 (grid 256 = 1 block/CU) + fp32 reduce.
#define B_DIM 8192
#define I_DIM 1024
#define O_DIM 1024
#define K_DIM 9216   // 9 * 1024

#define BM 256
#define BN 256
#define BK 64

typedef unsigned short ushort_t;
typedef __attribute__((ext_vector_type(8))) short short8;
typedef __attribute__((ext_vector_type(4))) float f32x4;

#define MFMA(a, b, c) __builtin_amdgcn_mfma_f32_16x16x32_bf16((a), (b), (c), 0, 0, 0)

__device__ __forceinline__ ushort_t f2bf(float f) {
    unsigned u = __float_as_uint(f);
    unsigned r = 0x7fffu + ((u >> 16) & 1u);
    return (ushort_t)((u + r) >> 16);
}

__device__ __forceinline__ void llds16(const ushort_t* g, ushort_t* l) {
    __builtin_amdgcn_global_load_lds(
        (const __attribute__((address_space(1))) unsigned int*)g,
        (__attribute__((address_space(3))) unsigned int*)l,
        16, 0, 0);
}

// ---------------- expansion: weights ----------------
__global__ __launch_bounds__(256) void expand_w_kernel(
        const float* __restrict__ bw, const float* __restrict__ sw,
        ushort_t* __restrict__ Wf) {
    int idx = blockIdx.x * 256 + threadIdx.x;   // one thread: (o, 2 consecutive i)
    int o = idx >> 9;
    int i = (idx & 511) << 1;
    ushort_t* out = Wf + (size_t)o * K_DIM + i;
    const float* bp = bw + ((size_t)o << 10) + i;
    *(unsigned*)out = (unsigned)f2bf(bp[0]) | ((unsigned)f2bf(bp[1]) << 16);
    const float* sp = sw + (((size_t)o << 10) + i) * 8;   // 16 contiguous floats
    float v[16];
    #pragma unroll
    for (int n = 0; n < 16; ++n) v[n] = sp[n];
    #pragma unroll
    for (int n = 0; n < 8; ++n)
        *(unsigned*)(out + (size_t)(n + 1) * 1024) =
            (unsigned)f2bf(v[n]) | ((unsigned)f2bf(v[8 + n]) << 16);
}

// ---------------- expansion: activations ----------------
__global__ __launch_bounds__(256) void expand_a_kernel(
        const float* __restrict__ x, ushort_t* __restrict__ Af) {
    int idx = blockIdx.x * 256 + threadIdx.x;   // one thread: (b, 2 consecutive i)
    int b = idx >> 9;
    int i = (idx & 511) << 1;
    const float* xp = x + ((size_t)b << 10) + i;
    float x0 = xp[0], x1 = xp[1];
    ushort_t* out = Af + (size_t)b * K_DIM + i;
    float s0 = x0 / (1.0f + __expf(-x0));
    float s1 = x1 / (1.0f + __expf(-x1));
    *(unsigned*)out = (unsigned)f2bf(s0) | ((unsigned)f2bf(s1) << 16);
    // quadratic B-spline basis, uniform knots -9..9 step 1.8
    float t0 = (x0 + 9.0f) * (1.0f / 1.8f);
    float t1 = (x1 + 9.0f) * (1.0f / 1.8f);
    float fj0 = floorf(t0), fj1 = floorf(t1);
    int j0 = (int)fj0, j1 = (int)fj1;
    float u0 = t0 - fj0, u1 = t1 - fj1;
    float p0 = 0.5f * (1.f - u0) * (1.f - u0);
    float p1 = 0.5f * (-2.f * u0 * u0 + 2.f * u0 + 1.f);
    float p2 = 0.5f * u0 * u0;
    float q0 = 0.5f * (1.f - u1) * (1.f - u1);
    float q1 = 0.5f * (-2.f * u1 * u1 + 2.f * u1 + 1.f);
    float q2 = 0.5f * u1 * u1;
    #pragma unroll
    for (int n = 0; n < 8; ++n) {
        float v0 = (n == j0 - 2) ? p0 : (n == j0 - 1) ? p1 : (n == j0) ? p2 : 0.f;
        float v1 = (n == j1 - 2) ? q0 : (n == j1 - 1) ? q1 : (n == j1) ? q2 : 0.f;
        *(unsigned*)(out + (size_t)(n + 1) * 1024) =
            (unsigned)f2bf(v0) | ((unsigned)f2bf(v1) << 16);
    }
}

// ---------------- GEMM: out[M=8192, N=1024] = Af[M,K] * Wf[N,K]^T ----------------
// grid = 128 * nsplit; wgid = split*128 + bm*4 + bn.
__global__ __launch_bounds__(512, 1) void gemm_bt(
        const ushort_t* __restrict__ Af,
        const ushort_t* __restrict__ Wf,
        float* __restrict__ out, float* __restrict__ part1,
        int kTiles) {
    // A ring-3 (96KB, prefetch distance 2) + B dbuf (64KB, distance 1) = 160KiB
    __shared__ __align__(16) ushort_t As[3][BM * BK];
    __shared__ __align__(16) ushort_t Bs[2][BN * BK];

    const int tid = threadIdx.x;

    // T1: bijective XCD swizzle (nwg divisible by 8)
    const int nwg = gridDim.x;
    const int orig = blockIdx.x;
    const int wgid = (orig & 7) * (nwg >> 3) + (orig >> 3);
    const int split = wgid >> 7;            // 128 blocks per split
    const int bm = (wgid & 127) >> 2;       // 0..31
    const int bn = wgid & 3;                // 0..3
    const int mBase = bm * BM, nBase = bn * BN;
    const size_t kOff = (size_t)split * kTiles * BK;

    const int lane = tid & 63;
    const int w = tid >> 6;                 // 8 waves: 2M x 4N -> 128x64 per wave
    const int wr = (w >> 2) * 128;
    const int wc = (w & 3) * 64;
    const int fr = lane & 15;
    const int kg = lane >> 4;               // k-group 0..3

    // staging: 512 threads x 16B = 8KB per round = 64 rows of 128B; 4 rounds each.
    // T2 swizzle: 16B slot ^= (row&7); source pre-swizzled, LDS dest linear.
    const int srow = tid >> 3;                                  // 0..63
    const int scolE = (((tid & 7) ^ (srow & 7)) << 3);          // pre-swizzled source col
    const int sdst = (tid & ~63) * 8;                           // wave-uniform elem offset

    auto stageA = [&](int t, int buf, int rnd) {
        const ushort_t* g = Af + (size_t)(mBase + rnd * 64 + srow) * K_DIM
                               + kOff + (size_t)t * BK + scolE;
        llds16(g, &As[buf][rnd * 4096 + sdst]);
    };
    auto stageB = [&](int t, int buf, int rnd) {
        const ushort_t* g = Wf + (size_t)(nBase + rnd * 64 + srow) * K_DIM
                               + kOff + (size_t)t * BK + scolE;
        llds16(g, &Bs[buf][rnd * 4096 + sdst]);
    };

    // read-side swizzled 16B-slot offsets: row&7 == fr&7 (wr, wc, 16*m all mult of 16)
    const int swz0 = ((kg ^ (fr & 7)) << 3);          // kk = 0
    const int swz1 = (((4 + kg) ^ (fr & 7)) << 3);    // kk = 1

    f32x4 acc[8][4];
    #pragma unroll
    for (int m = 0; m < 8; ++m)
        #pragma unroll
        for (int n = 0; n < 4; ++n) acc[m][n] = (f32x4){0.f, 0.f, 0.f, 0.f};

    // prologue (FIFO order matters for vmcnt(4)): B(0), A(0), A(1)
    stageB(0, 0, 0); stageB(0, 0, 1); stageB(0, 0, 2); stageB(0, 0, 3);
    stageA(0, 0, 0); stageA(0, 0, 1); stageA(0, 0, 2); stageA(0, 0, 3);
    stageA(1, 1, 0); stageA(1, 1, 1); stageA(1, 1, 2); stageA(1, 1, 3);

    int ca = 0;   // A ring slot holding tile t
    for (int t = 0; t < kTiles; ++t) {
        // drain all but the newest 4 gloads (= A(t+1)); A(t), B(t) resident
        if (t + 1 < kTiles) asm volatile("s_waitcnt vmcnt(4)" ::: "memory");
        else                asm volatile("s_waitcnt vmcnt(0)" ::: "memory");
        __builtin_amdgcn_s_barrier();

        const int pa = (ca >= 1) ? ca - 1 : 2;   // (ca+2)%3
        const ushort_t* A_ = As[ca];
        const ushort_t* B_ = Bs[t & 1];

        // ---- phase 0: issue B(t+1); hoist b[4][2]; MFMA m=0,1 ----
        if (t + 1 < kTiles) {
            stageB(t + 1, (t + 1) & 1, 0); stageB(t + 1, (t + 1) & 1, 1);
            stageB(t + 1, (t + 1) & 1, 2); stageB(t + 1, (t + 1) & 1, 3);
        }
        short8 b[4][2];
        #pragma unroll
        for (int n = 0; n < 4; ++n) {
            int brow = (wc + n * 16 + fr) * BK;
            b[n][0] = *(const short8*)&B_[brow + swz0];
            b[n][1] = *(const short8*)&B_[brow + swz1];
        }
        {
            short8 a[2][2];
            #pragma unroll
            for (int m = 0; m < 2; ++m) {
                int arow = (wr + m * 16 + fr) * BK;
                a[m][0] = *(const short8*)&A_[arow + swz0];
                a[m][1] = *(const short8*)&A_[arow + swz1];
            }
            asm volatile("s_waitcnt lgkmcnt(0)" ::: "memory");
            __builtin_amdgcn_sched_barrier(0);
            __builtin_amdgcn_s_setprio(1);
            #pragma unroll
            for (int m = 0; m < 2; ++m)
                #pragma unroll
                for (int n = 0; n < 4; ++n) {
                    acc[m][n] = MFMA(a[m][0], b[n][0], acc[m][n]);
                    acc[m][n] = MFMA(a[m][1], b[n][1], acc[m][n]);
                }
            __builtin_amdgcn_s_setprio(0);
        }

        // ---- phase 1: issue A(t+2); MFMA m=2,3 ----
        if (t + 2 < kTiles) {
            stageA(t + 2, pa, 0); stageA(t + 2, pa, 1);
            stageA(t + 2, pa, 2); stageA(t + 2, pa, 3);
        }
        {
            short8 a[2][2];
            #pragma unroll
            for (int m = 0; m < 2; ++m) {
                int arow = (wr + (2 + m) * 16 + fr) * BK;
                a[m][0] = *(const short8*)&A_[arow + swz0];
                a[m][1] = *(const short8*)&A_[arow + swz1];
            }
            asm volatile("s_waitcnt lgkmcnt(0)" ::: "memory");
            __builtin_amdgcn_sched_barrier(0);
            __builtin_amdgcn_s_setprio(1);
            #pragma unroll
            for (int m = 0; m < 2; ++m)
                #pragma unroll
                for (int n = 0; n < 4; ++n) {
                    acc[2 + m][n] = MFMA(a[m][0], b[n][0], acc[2 + m][n]);
                    acc[2 + m][n] = MFMA(a[m][1], b[n][1], acc[2 + m][n]);
                }
            __builtin_amdgcn_s_setprio(0);
        }
        __builtin_amdgcn_s_barrier();   // mid-tile pacing

        // ---- phase 2: MFMA m=4,5 ----
        {
            short8 a[2][2];
            #pragma unroll
            for (int m = 0; m < 2; ++m) {
                int arow = (wr + (4 + m) * 16 + fr) * BK;
                a[m][0] = *(const short8*)&A_[arow + swz0];
                a[m][1] = *(const short8*)&A_[arow + swz1];
            }
            asm volatile("s_waitcnt lgkmcnt(0)" ::: "memory");
            __builtin_amdgcn_sched_barrier(0);
            __builtin_amdgcn_s_setprio(1);
            #pragma unroll
            for (int m = 0; m < 2; ++m)
                #pragma unroll
                for (int n = 0; n < 4; ++n) {
                    acc[4 + m][n] = MFMA(a[m][0], b[n][0], acc[4 + m][n]);
                    acc[4 + m][n] = MFMA(a[m][1], b[n][1], acc[4 + m][n]);
                }
            __builtin_amdgcn_s_setprio(0);
        }

        // ---- phase 3: MFMA m=6,7 ----
        {
            short8 a[2][2];
            #pragma unroll
            for (int m = 0; m < 2; ++m) {
                int arow = (wr + (6 + m) * 16 + fr) * BK;
                a[m][0] = *(const short8*)&A_[arow + swz0];
                a[m][1] = *(const short8*)&A_[arow + swz1];
            }
            asm volatile("s_waitcnt lgkmcnt(0)" ::: "memory");
            __builtin_amdgcn_sched_barrier(0);
            __builtin_amdgcn_s_setprio(1);
            #pragma unroll
            for (int m = 0; m < 2; ++m)
                #pragma unroll
                for (int n = 0; n < 4; ++n) {
                    acc[6 + m][n] = MFMA(a[m][0], b[n][0], acc[6 + m][n]);
                    acc[6 + m][n] = MFMA(a[m][1], b[n][1], acc[6 + m][n]);
                }
            __builtin_amdgcn_s_setprio(0);
        }

        ca = (ca + 1 == 3) ? 0 : ca + 1;
    }

    // epilogue: C/D layout col=lane&15, row=(lane>>4)*4+r
    float* obase = split ? part1 : out;
    const int orow = (lane >> 4) * 4;
    const int ocol = lane & 15;
    #pragma unroll
    for (int m = 0; m < 8; ++m)
        #pragma unroll
        for (int n = 0; n < 4; ++n) {
            size_t base = (size_t)(mBase + wr + m * 16 + orow) * O_DIM
                        + (nBase + wc + n * 16 + ocol);
            #pragma unroll
            for (int r = 0; r < 4; ++r)
                obase[base + (size_t)r * O_DIM] = acc[m][n][r];
        }
}

// ---------------- reduce: out += part1 (float4) ----------------
__global__ __launch_bounds__(256) void reduce_kernel(
        float* __restrict__ out, const float* __restrict__ p1) {
    int i = blockIdx.x * 256 + threadIdx.x;   // float4 index, 2M total
    f32x4 a = ((const f32x4*)out)[i];
    f32x4 b = ((const f32x4*)p1)[i];
    ((f32x4*)out)[i] = a + b;
}

extern "C" void kernel_launch(void* const* d_in, const int* in_sizes, int n_in,
                              void* d_out, int out_size, void* d_ws, size_t ws_size,
                              hipStream_t stream) {
    const float* x  = (const float*)d_in[0];
    const float* bw = (const float*)d_in[1];
    const float* sw = (const float*)d_in[2];
    float* out = (float*)d_out;

    // ws layout: Wf [1024 x 9216] bf16 (18.9 MB), Af [8192 x 9216] bf16 (151 MB),
    // part1 [8192 x 1024] fp32 (33.6 MB)
    const size_t nW = (size_t)O_DIM * K_DIM;
    const size_t nA = (size_t)B_DIM * K_DIM;
    ushort_t* Wf = (ushort_t*)d_ws;
    ushort_t* Af = Wf + nW;
    float* part1 = (float*)(Af + nA);
    const size_t need = (nW + nA) * 2 + (size_t)B_DIM * O_DIM * 4;

    const int nsplit = (ws_size >= need) ? 2 : 1;   // ws_size constant -> deterministic
    const int kTiles = (K_DIM / BK) / nsplit;       // 72 or 144
    const int nwg = 128 * nsplit;

    expand_w_kernel<<<(O_DIM * I_DIM / 2) / 256, 256, 0, stream>>>(bw, sw, Wf);
    expand_a_kernel<<<(B_DIM * I_DIM / 2) / 256, 256, 0, stream>>>(x, Af);
    gemm_bt<<<nwg, 512, 0, stream>>>(Af, Wf, out, part1, kTiles);
    if (nsplit == 2)
        reduce_kernel<<<(B_DIM * O_DIM / 4) / 256, 256, 0, stream>>>(out, part1);
}